// Round 4
// baseline (219.890 us; speedup 1.0000x reference)
//
#include <hip/hip_runtime.h>

typedef float vf4 __attribute__((ext_vector_type(4)));
typedef float vf4u __attribute__((ext_vector_type(4), aligned(4)));

// ======================================================================
// Compile-time CG table (validated rounds 1-3): real-SH CG build in fp64
// via constexpr. Coefficients fold to literals; zeros DCE away.
// ======================================================================
namespace cgc {

struct FTab { double f[13]; };
constexpr FTab mkft(){ FTab t{}; t.f[0]=1.0; for(int i=1;i<13;i++) t.f[i]=t.f[i-1]*i; return t; }
constexpr FTab FTB = mkft();

constexpr double csqrt(double x){
  double g = x < 1.0 ? 1.0 : x;
  for(int i=0;i<40;i++) g = 0.5*(g + x/g);
  return g;
}

constexpr double cgcoef(int j1,int m1,int j2,int m2,int j3,int m3){
  if (m1+m2 != m3) return 0.0;
  double pref = csqrt((double)(2*j3+1) * FTB.f[j3+j1-j2] * FTB.f[j3-j1+j2]
                      * FTB.f[j1+j2-j3] / FTB.f[j1+j2+j3+1]);
  pref *= csqrt(FTB.f[j3+m3]*FTB.f[j3-m3]*FTB.f[j1-m1]*FTB.f[j1+m1]
                *FTB.f[j2-m2]*FTB.f[j2+m2]);
  double s = 0.0;
  for(int k=0;k<=j1+j2-j3;k++){
    int e1=j1+j2-j3-k, e2=j1-m1-k, e3=j2+m2-k, e4=j3-j2+m1+k, e5=j3-j1-m2+k;
    if (e1<0||e2<0||e3<0||e4<0||e5<0) continue;
    double prod = FTB.f[k]*FTB.f[e1]*FTB.f[e2]*FTB.f[e3]*FTB.f[e4]*FTB.f[e5];
    s += (k&1) ? (-1.0/prod) : (1.0/prod);
  }
  return pref*s;
}

struct Tab { double v[11][125]; };

constexpr Tab build(){
  Tab T{};
  constexpr int PL1[11]={0,0,0,1,1,1,1,2,2,2,2};
  constexpr int PL2[11]={0,1,2,0,1,1,2,0,1,2,2};
  constexpr int PL3[11]={0,1,2,1,0,2,1,2,1,0,2};
  constexpr int NOUT[3]={3,4,4};
  double qr[3][5][5]{}, qi[3][5][5]{};
  for(int l=0;l<3;l++){
    const double is2 = 0.70710678118654752440;
    for(int m=-l;m<0;m++){ qr[l][l+m][l-m]=is2; qi[l][l+m][l+m]=-is2; }
    qr[l][l][l]=1.0;
    for(int m=1;m<=l;m++){ double sg=(m&1)?-1.0:1.0; qr[l][l+m][l+m]=sg*is2; qi[l][l+m][l-m]=sg*is2; }
    if (l==1){ for(int a=0;a<5;a++)for(int b=0;b<5;b++){ double re=qr[1][a][b], im=qi[1][a][b]; qr[1][a][b]=im; qi[1][a][b]=-re; } }
    if (l==2){ for(int a=0;a<5;a++)for(int b=0;b<5;b++){ qr[2][a][b]=-qr[2][a][b]; qi[2][a][b]=-qi[2][a][b]; } }
  }
  for(int p=0;p<11;p++){
    int l1=PL1[p], l2=PL2[p], l3=PL3[p];
    int d1=2*l1+1, d2=2*l2+1, d3=2*l3+1;
    double cs[125]{};
    for(int i=0;i<d1;i++)for(int k=0;k<d2;k++)for(int m=0;m<d3;m++)
      cs[(i*d2+k)*d3+m] = cgcoef(l1,i-l1,l2,k-l2,l3,m-l3);
    double nrm2 = 0.0;
    for(int j=0;j<d1;j++)for(int lc=0;lc<d2;lc++)for(int n=0;n<d3;n++){
      double ar = 0.0;
      for(int i=0;i<d1;i++){
        double q1r=qr[l1][i][j], q1i=qi[l1][i][j];
        if (q1r==0.0 && q1i==0.0) continue;
        for(int k=0;k<d2;k++){
          double q2r=qr[l2][k][lc], q2i=qi[l2][k][lc];
          if (q2r==0.0 && q2i==0.0) continue;
          double abr=q1r*q2r-q1i*q2i, abi=q1r*q2i+q1i*q2r;
          for(int m=0;m<d3;m++){
            double c=cs[(i*d2+k)*d3+m];
            if (c==0.0) continue;
            double q3r=qr[l3][m][n], q3i=-qi[l3][m][n];   // conj(q3)
            ar += (abr*q3r - abi*q3i)*c;
          }
        }
      }
      T.v[p][(j*d2+lc)*d3+n] = ar;
      nrm2 += ar*ar;
    }
    double sc = csqrt((double)(2*l3+1)/(double)NOUT[l3]) / csqrt(nrm2);
    for(int e=0;e<d1*d2*d3;e++) T.v[p][e] *= sc;
  }
  return T;
}

constexpr Tab CGT = build();

} // namespace cgc

// ======================================================================
// Sparse per-path TP: coefficients are literals, zeros DCE'd.
// ======================================================================
template<int P,int L1,int L2,int L3>
__device__ __forceinline__ void tp_path(float wp, const float (&xi)[9],
                                        const float (&yi)[9], float (&o)[9])
{
  constexpr int D1=2*L1+1, D2=2*L2+1, D3=2*L3+1, O1=L1*L1, O2=L2*L2, O3=L3*L3;
  float z[D3];
#pragma unroll
  for(int k=0;k<D3;k++) z[k]=0.f;
#pragma unroll
  for(int i=0;i<D1;i++){
#pragma unroll
    for(int j=0;j<D2;j++){
      const float tt = xi[O1+i]*yi[O2+j];
#pragma unroll
      for(int k=0;k<D3;k++){
        const double cv = cgc::CGT.v[P][(i*D2+j)*D3+k];
        if (cv > 1e-12 || cv < -1e-12)
          z[k] = fmaf((float)cv, tt, z[k]);
      }
    }
  }
#pragma unroll
  for(int k=0;k<D3;k++) o[O3+k] = fmaf(wp, z[k], o[O3+k]);
}

// ======================================================================
// Fused kernel, R3 math, restructured VMEM issue:
//  - dist tile staged to LDS (removes HBM latency from linear loop)
//  - x/y prefetches staggered (r0,r1 pre-bar; r2 @ linear-h0; r3 @ h1)
//    so every phase has outstanding VMEM -> MLP covers HBM latency
//  - nontemporal stores (out never re-read; keep L3 for x/y stream)
//  - launch_bounds(256,3): VGPR cap 170, est. peak ~156, no spill
// ======================================================================
__global__ __launch_bounds__(256, 3) void e3_tp_kernel(
    const float* __restrict__ x, const float* __restrict__ y,
    const float* __restrict__ dist, const float* __restrict__ Wl,
    const float* __restrict__ bias, float* __restrict__ out)
{
  __shared__ float Ws[16*32*12];   // W half-tile [f=16][c=32][12], 24 KB
  __shared__ float Dl[32*32];      // dist tile [b=32][f=32], 4 KB
  const vf4* Ws4 = (const vf4*)Ws;
  const int t = threadIdx.x;
  const int c = t & 31, g = t >> 5;
  const long bblk = (long)blockIdx.x * 32;
  const long b0 = bblk + g*4;
  const long ib = b0*32 + c;

  auto loadvec9 = [](const float* p, float (&v)[9]) {
    vf4 a_, b_;
    __builtin_memcpy(&a_, p,   16);
    __builtin_memcpy(&b_, p+4, 16);
    v[0]=a_.x; v[1]=a_.y; v[2]=a_.z; v[3]=a_.w;
    v[4]=b_.x; v[5]=b_.y; v[6]=b_.z; v[7]=b_.w; v[8]=p[8];
  };

  auto stage_half = [&](int half) {
#pragma unroll
    for (int q = 0; q < 2; q++){
      const int pr = t + q*256;
      const int f = pr >> 5, cc = pr & 31;
      const float* src = Wl + (half*16 + f)*352 + cc*11;
      float*       dst = Ws + f*384 + cc*12;
      vf4 a_, b_;
      __builtin_memcpy(&a_, src,   16);
      __builtin_memcpy(&b_, src+4, 16);
      *(vf4*)(dst)   = a_;
      *(vf4*)(dst+4) = b_;
      dst[8] = src[8]; dst[9] = src[9]; dst[10] = src[10];
    }
  };

  float w[4][11];

  auto linear_half = [&](int half) {
    const vf4* wsrow = Ws4 + c*3;
#pragma unroll 1
    for (int fq = 0; fq < 4; fq++){
      vf4 dd[4];
#pragma unroll
      for (int r = 0; r < 4; r++)
        dd[r] = *(const vf4*)(Dl + (g*4+r)*32 + half*16 + fq*4);
#pragma unroll
      for (int ff = 0; ff < 4; ff++){
        const vf4* wr = wsrow + (fq*4 + ff)*96;   // f stride = 384 fl = 96 vf4
        const vf4 wa = wr[0], wb2 = wr[1], wc2 = wr[2];
        const float wl[11] = {wa.x,wa.y,wa.z,wa.w, wb2.x,wb2.y,wb2.z,wb2.w,
                              wc2.x,wc2.y,wc2.z};
#pragma unroll
        for (int r = 0; r < 4; r++){
          const float dv = (ff==0) ? dd[r].x : (ff==1) ? dd[r].y
                         : (ff==2) ? dd[r].z : dd[r].w;
#pragma unroll
          for (int p = 0; p < 11; p++) w[r][p] = fmaf(dv, wl[p], w[r][p]);
        }
      }
    }
  };

  // ---- stage dist tile + W half 0, prefetch x/y r0,r1 and bias ----
  {
    vf4 dv; __builtin_memcpy(&dv, dist + bblk*32 + t*4, 16);
    *(vf4*)(Dl + t*4) = dv;
  }
  stage_half(0);

  float xi0[9], yi0[9], xi1[9], yi1[9], xi2[9], yi2[9], xi3[9], yi3[9];
  loadvec9(x + ib*9,       xi0);
  loadvec9(y + ib*9,       yi0);
  loadvec9(x + ib*9 + 288, xi1);
  loadvec9(y + ib*9 + 288, yi1);

  {
    const float* bp = bias + c*11;
    vf4 ba, bb2;
    __builtin_memcpy(&ba,  bp,   16);
    __builtin_memcpy(&bb2, bp+4, 16);
    const float bl[11] = {ba.x,ba.y,ba.z,ba.w, bb2.x,bb2.y,bb2.z,bb2.w,
                          bp[8], bp[9], bp[10]};
#pragma unroll
    for (int p = 0; p < 11; p++){
#pragma unroll
      for (int r = 0; r < 4; r++) w[r][p] = bl[p];
    }
  }

  __syncthreads();                       // B1: Ws h0 + Dl ready

  // ---- linear half 0 (r2 prefetch outstanding during it) ----
  loadvec9(x + ib*9 + 576, xi2);
  loadvec9(y + ib*9 + 576, yi2);
  linear_half(0);

  __syncthreads();                       // B2: all h0 reads done
  stage_half(1);
  __syncthreads();                       // B3: Ws h1 ready

  // ---- linear half 1 (r3 prefetch outstanding during it) ----
  loadvec9(x + ib*9 + 864, xi3);
  loadvec9(y + ib*9 + 864, yi3);
  linear_half(1);

  // ---- per-item tensor product + nontemporal stores ----
  float* op = out + ib*9;

  auto tpstore = [&](const float (&xi)[9], const float (&yi)[9],
                     const float (&wr)[11], float* o0) {
    float o[9];
#pragma unroll
    for (int k = 0; k < 9; k++) o[k] = 0.f;
    tp_path<0, 0,0,0>(wr[0],  xi, yi, o);
    tp_path<1, 0,1,1>(wr[1],  xi, yi, o);
    tp_path<2, 0,2,2>(wr[2],  xi, yi, o);
    tp_path<3, 1,0,1>(wr[3],  xi, yi, o);
    tp_path<4, 1,1,0>(wr[4],  xi, yi, o);
    tp_path<5, 1,1,2>(wr[5],  xi, yi, o);
    tp_path<6, 1,2,1>(wr[6],  xi, yi, o);
    tp_path<7, 2,0,2>(wr[7],  xi, yi, o);
    tp_path<8, 2,1,1>(wr[8],  xi, yi, o);
    tp_path<9, 2,2,0>(wr[9],  xi, yi, o);
    tp_path<10,2,2,2>(wr[10], xi, yi, o);
    vf4 s0 = { o[0], o[1], o[2], o[3] };
    vf4 s1 = { o[4], o[5], o[6], o[7] };
    __builtin_nontemporal_store(s0, (vf4u*)(o0));
    __builtin_nontemporal_store(s1, (vf4u*)(o0 + 4));
    __builtin_nontemporal_store(o[8], o0 + 8);
  };

  tpstore(xi0, yi0, w[0], op);
  tpstore(xi1, yi1, w[1], op + 288);
  tpstore(xi2, yi2, w[2], op + 576);
  tpstore(xi3, yi3, w[3], op + 864);
}

extern "C" void kernel_launch(void* const* d_in, const int* in_sizes, int n_in,
                              void* d_out, int out_size, void* d_ws, size_t ws_size,
                              hipStream_t stream)
{
  const float* x    = (const float*)d_in[0];
  const float* y    = (const float*)d_in[1];
  const float* dist = (const float*)d_in[2];
  const float* Wl   = (const float*)d_in[3];
  const float* bl   = (const float*)d_in[4];
  float* out = (float*)d_out;

  const int B = in_sizes[2] / 32;        // 131072 rows
  const int nblocks = B / 32;            // 32 b's x 32 c's per block
  hipLaunchKernelGGL(e3_tp_kernel, dim3(nblocks), dim3(256), 0, stream,
                     x, y, dist, Wl, bl, out);
}

// Round 5
// 161.077 us; speedup vs baseline: 1.3651x; 1.3651x over previous
//
#include <hip/hip_runtime.h>

typedef float vf4 __attribute__((ext_vector_type(4)));

// ======================================================================
// Compile-time CG table (validated rounds 1-4): real-SH CG build in fp64
// via constexpr. Coefficients fold to literals; zeros DCE away.
// ======================================================================
namespace cgc {

struct FTab { double f[13]; };
constexpr FTab mkft(){ FTab t{}; t.f[0]=1.0; for(int i=1;i<13;i++) t.f[i]=t.f[i-1]*i; return t; }
constexpr FTab FTB = mkft();

constexpr double csqrt(double x){
  double g = x < 1.0 ? 1.0 : x;
  for(int i=0;i<40;i++) g = 0.5*(g + x/g);
  return g;
}

constexpr double cgcoef(int j1,int m1,int j2,int m2,int j3,int m3){
  if (m1+m2 != m3) return 0.0;
  double pref = csqrt((double)(2*j3+1) * FTB.f[j3+j1-j2] * FTB.f[j3-j1+j2]
                      * FTB.f[j1+j2-j3] / FTB.f[j1+j2+j3+1]);
  pref *= csqrt(FTB.f[j3+m3]*FTB.f[j3-m3]*FTB.f[j1-m1]*FTB.f[j1+m1]
                *FTB.f[j2-m2]*FTB.f[j2+m2]);
  double s = 0.0;
  for(int k=0;k<=j1+j2-j3;k++){
    int e1=j1+j2-j3-k, e2=j1-m1-k, e3=j2+m2-k, e4=j3-j2+m1+k, e5=j3-j1-m2+k;
    if (e1<0||e2<0||e3<0||e4<0||e5<0) continue;
    double prod = FTB.f[k]*FTB.f[e1]*FTB.f[e2]*FTB.f[e3]*FTB.f[e4]*FTB.f[e5];
    s += (k&1) ? (-1.0/prod) : (1.0/prod);
  }
  return pref*s;
}

struct Tab { double v[11][125]; };

constexpr Tab build(){
  Tab T{};
  constexpr int PL1[11]={0,0,0,1,1,1,1,2,2,2,2};
  constexpr int PL2[11]={0,1,2,0,1,1,2,0,1,2,2};
  constexpr int PL3[11]={0,1,2,1,0,2,1,2,1,0,2};
  constexpr int NOUT[3]={3,4,4};
  double qr[3][5][5]{}, qi[3][5][5]{};
  for(int l=0;l<3;l++){
    const double is2 = 0.70710678118654752440;
    for(int m=-l;m<0;m++){ qr[l][l+m][l-m]=is2; qi[l][l+m][l+m]=-is2; }
    qr[l][l][l]=1.0;
    for(int m=1;m<=l;m++){ double sg=(m&1)?-1.0:1.0; qr[l][l+m][l+m]=sg*is2; qi[l][l+m][l-m]=sg*is2; }
    if (l==1){ for(int a=0;a<5;a++)for(int b=0;b<5;b++){ double re=qr[1][a][b], im=qi[1][a][b]; qr[1][a][b]=im; qi[1][a][b]=-re; } }
    if (l==2){ for(int a=0;a<5;a++)for(int b=0;b<5;b++){ qr[2][a][b]=-qr[2][a][b]; qi[2][a][b]=-qi[2][a][b]; } }
  }
  for(int p=0;p<11;p++){
    int l1=PL1[p], l2=PL2[p], l3=PL3[p];
    int d1=2*l1+1, d2=2*l2+1, d3=2*l3+1;
    double cs[125]{};
    for(int i=0;i<d1;i++)for(int k=0;k<d2;k++)for(int m=0;m<d3;m++)
      cs[(i*d2+k)*d3+m] = cgcoef(l1,i-l1,l2,k-l2,l3,m-l3);
    double nrm2 = 0.0;
    for(int j=0;j<d1;j++)for(int lc=0;lc<d2;lc++)for(int n=0;n<d3;n++){
      double ar = 0.0;
      for(int i=0;i<d1;i++){
        double q1r=qr[l1][i][j], q1i=qi[l1][i][j];
        if (q1r==0.0 && q1i==0.0) continue;
        for(int k=0;k<d2;k++){
          double q2r=qr[l2][k][lc], q2i=qi[l2][k][lc];
          if (q2r==0.0 && q2i==0.0) continue;
          double abr=q1r*q2r-q1i*q2i, abi=q1r*q2i+q1i*q2r;
          for(int m=0;m<d3;m++){
            double c=cs[(i*d2+k)*d3+m];
            if (c==0.0) continue;
            double q3r=qr[l3][m][n], q3i=-qi[l3][m][n];   // conj(q3)
            ar += (abr*q3r - abi*q3i)*c;
          }
        }
      }
      T.v[p][(j*d2+lc)*d3+n] = ar;
      nrm2 += ar*ar;
    }
    double sc = csqrt((double)(2*l3+1)/(double)NOUT[l3]) / csqrt(nrm2);
    for(int e=0;e<d1*d2*d3;e++) T.v[p][e] *= sc;
  }
  return T;
}

constexpr Tab CGT = build();

} // namespace cgc

// ======================================================================
// Sparse per-path TP: coefficients are literals, zeros DCE'd.
// ======================================================================
template<int P,int L1,int L2,int L3>
__device__ __forceinline__ void tp_path(float wp, const float (&xi)[9],
                                        const float (&yi)[9], float (&o)[9])
{
  constexpr int D1=2*L1+1, D2=2*L2+1, D3=2*L3+1, O1=L1*L1, O2=L2*L2, O3=L3*L3;
  float z[D3];
#pragma unroll
  for(int k=0;k<D3;k++) z[k]=0.f;
#pragma unroll
  for(int i=0;i<D1;i++){
#pragma unroll
    for(int j=0;j<D2;j++){
      const float tt = xi[O1+i]*yi[O2+j];
#pragma unroll
      for(int k=0;k<D3;k++){
        const double cv = cgc::CGT.v[P][(i*D2+j)*D3+k];
        if (cv > 1e-12 || cv < -1e-12)
          z[k] = fmaf((float)cv, tt, z[k]);
      }
    }
  }
#pragma unroll
  for(int k=0;k<D3;k++) o[O3+k] = fmaf(wp, z[k], o[O3+k]);
}

struct Vec9 { vf4 a, b; float s; };

// ======================================================================
// Fused kernel. R3's proven memory path (plain stores) + forced early
// x/y prefetch: all 8 vec9 loads issued before barrier 1 and PINNED in
// VGPRs with asm keep-alives so the compiler cannot sink them. The
// linear (LDS W + LDS dist) then runs while x/y are in flight; the TP
// phase has zero load stalls.
// ======================================================================
__global__ __launch_bounds__(256, 3) void e3_tp_kernel(
    const float* __restrict__ x, const float* __restrict__ y,
    const float* __restrict__ dist, const float* __restrict__ Wl,
    const float* __restrict__ bias, float* __restrict__ out)
{
  __shared__ float Ws[16*32*12];   // W half-tile [f=16][c=32][12], 24 KB
  __shared__ float Dl[32*32];      // dist tile [b=32][f=32], 4 KB
  const vf4* Ws4 = (const vf4*)Ws;
  const int t = threadIdx.x;
  const int c = t & 31, g = t >> 5;
  const long bblk = (long)blockIdx.x * 32;
  const long b0 = bblk + g*4;
  const long ib = b0*32 + c;

  auto ldv9 = [](const float* p) {
    Vec9 v;
    __builtin_memcpy(&v.a, p,   16);
    __builtin_memcpy(&v.b, p+4, 16);
    v.s = p[8];
    return v;
  };

  auto stage_half = [&](int half) {
#pragma unroll
    for (int q = 0; q < 2; q++){
      const int pr = t + q*256;
      const int f = pr >> 5, cc = pr & 31;
      const float* src = Wl + (half*16 + f)*352 + cc*11;
      float*       dst = Ws + f*384 + cc*12;
      vf4 a_, b_;
      __builtin_memcpy(&a_, src,   16);
      __builtin_memcpy(&b_, src+4, 16);
      *(vf4*)(dst)   = a_;
      *(vf4*)(dst+4) = b_;
      dst[8] = src[8]; dst[9] = src[9]; dst[10] = src[10];
    }
  };

  float w[4][11];

  auto linear_half = [&](int half) {
    const vf4* wsrow = Ws4 + c*3;
#pragma unroll 1
    for (int fq = 0; fq < 4; fq++){
      vf4 dd[4];
#pragma unroll
      for (int r = 0; r < 4; r++)
        dd[r] = *(const vf4*)(Dl + (g*4+r)*32 + half*16 + fq*4);
#pragma unroll
      for (int ff = 0; ff < 4; ff++){
        const vf4* wr = wsrow + (fq*4 + ff)*96;   // f stride = 384 fl = 96 vf4
        const vf4 wa = wr[0], wb2 = wr[1], wc2 = wr[2];
        const float wl[11] = {wa.x,wa.y,wa.z,wa.w, wb2.x,wb2.y,wb2.z,wb2.w,
                              wc2.x,wc2.y,wc2.z};
#pragma unroll
        for (int r = 0; r < 4; r++){
          const float dv = (ff==0) ? dd[r].x : (ff==1) ? dd[r].y
                         : (ff==2) ? dd[r].z : dd[r].w;
#pragma unroll
          for (int p = 0; p < 11; p++) w[r][p] = fmaf(dv, wl[p], w[r][p]);
        }
      }
    }
  };

  // ---- stage dist tile + W half 0 ----
  {
    vf4 dv; __builtin_memcpy(&dv, dist + bblk*32 + t*4, 16);
    *(vf4*)(Dl + t*4) = dv;
  }
  stage_half(0);

  // ---- issue ALL x/y loads now; pin so they can't be sunk ----
  Vec9 xv0 = ldv9(x + ib*9),       yv0 = ldv9(y + ib*9);
  Vec9 xv1 = ldv9(x + ib*9 + 288), yv1 = ldv9(y + ib*9 + 288);
  Vec9 xv2 = ldv9(x + ib*9 + 576), yv2 = ldv9(y + ib*9 + 576);
  Vec9 xv3 = ldv9(x + ib*9 + 864), yv3 = ldv9(y + ib*9 + 864);
  asm volatile("" : "+v"(xv0.a), "+v"(xv0.b), "+v"(xv0.s),
                    "+v"(yv0.a), "+v"(yv0.b), "+v"(yv0.s));
  asm volatile("" : "+v"(xv1.a), "+v"(xv1.b), "+v"(xv1.s),
                    "+v"(yv1.a), "+v"(yv1.b), "+v"(yv1.s));
  asm volatile("" : "+v"(xv2.a), "+v"(xv2.b), "+v"(xv2.s),
                    "+v"(yv2.a), "+v"(yv2.b), "+v"(yv2.s));
  asm volatile("" : "+v"(xv3.a), "+v"(xv3.b), "+v"(xv3.s),
                    "+v"(yv3.a), "+v"(yv3.b), "+v"(yv3.s));

  // ---- bias init ----
  {
    const float* bp = bias + c*11;
    vf4 ba, bb2;
    __builtin_memcpy(&ba,  bp,   16);
    __builtin_memcpy(&bb2, bp+4, 16);
    const float bl[11] = {ba.x,ba.y,ba.z,ba.w, bb2.x,bb2.y,bb2.z,bb2.w,
                          bp[8], bp[9], bp[10]};
#pragma unroll
    for (int p = 0; p < 11; p++){
#pragma unroll
      for (int r = 0; r < 4; r++) w[r][p] = bl[p];
    }
  }

  __syncthreads();                       // B1: Ws h0 + Dl ready
  linear_half(0);
  __syncthreads();                       // B2: all h0 reads done
  stage_half(1);
  __syncthreads();                       // B3: Ws h1 ready
  linear_half(1);

  // ---- per-item tensor product + plain stores ----
  float* op = out + ib*9;

  auto tpstore = [&](const Vec9& xv, const Vec9& yv,
                     const float (&wr)[11], float* o0) {
    const float xi[9] = {xv.a.x,xv.a.y,xv.a.z,xv.a.w,
                         xv.b.x,xv.b.y,xv.b.z,xv.b.w, xv.s};
    const float yi[9] = {yv.a.x,yv.a.y,yv.a.z,yv.a.w,
                         yv.b.x,yv.b.y,yv.b.z,yv.b.w, yv.s};
    float o[9];
#pragma unroll
    for (int k = 0; k < 9; k++) o[k] = 0.f;
    tp_path<0, 0,0,0>(wr[0],  xi, yi, o);
    tp_path<1, 0,1,1>(wr[1],  xi, yi, o);
    tp_path<2, 0,2,2>(wr[2],  xi, yi, o);
    tp_path<3, 1,0,1>(wr[3],  xi, yi, o);
    tp_path<4, 1,1,0>(wr[4],  xi, yi, o);
    tp_path<5, 1,1,2>(wr[5],  xi, yi, o);
    tp_path<6, 1,2,1>(wr[6],  xi, yi, o);
    tp_path<7, 2,0,2>(wr[7],  xi, yi, o);
    tp_path<8, 2,1,1>(wr[8],  xi, yi, o);
    tp_path<9, 2,2,0>(wr[9],  xi, yi, o);
    tp_path<10,2,2,2>(wr[10], xi, yi, o);
    vf4 s0 = { o[0], o[1], o[2], o[3] };
    vf4 s1 = { o[4], o[5], o[6], o[7] };
    __builtin_memcpy(o0,     &s0, 16);
    __builtin_memcpy(o0 + 4, &s1, 16);
    o0[8] = o[8];
  };

  tpstore(xv0, yv0, w[0], op);
  tpstore(xv1, yv1, w[1], op + 288);
  tpstore(xv2, yv2, w[2], op + 576);
  tpstore(xv3, yv3, w[3], op + 864);
}

extern "C" void kernel_launch(void* const* d_in, const int* in_sizes, int n_in,
                              void* d_out, int out_size, void* d_ws, size_t ws_size,
                              hipStream_t stream)
{
  const float* x    = (const float*)d_in[0];
  const float* y    = (const float*)d_in[1];
  const float* dist = (const float*)d_in[2];
  const float* Wl   = (const float*)d_in[3];
  const float* bl   = (const float*)d_in[4];
  float* out = (float*)d_out;

  const int B = in_sizes[2] / 32;        // 131072 rows
  const int nblocks = B / 32;            // 32 b's x 32 c's per block
  hipLaunchKernelGGL(e3_tp_kernel, dim3(nblocks), dim3(256), 0, stream,
                     x, y, dist, Wl, bl, out);
}

// Round 6
// 158.874 us; speedup vs baseline: 1.3840x; 1.0139x over previous
//
#include <hip/hip_runtime.h>

typedef float vf4 __attribute__((ext_vector_type(4)));

// ======================================================================
// Compile-time CG table (validated rounds 1-5): real-SH CG build in fp64
// via constexpr. Coefficients fold to literals; zeros DCE away.
// ======================================================================
namespace cgc {

struct FTab { double f[13]; };
constexpr FTab mkft(){ FTab t{}; t.f[0]=1.0; for(int i=1;i<13;i++) t.f[i]=t.f[i-1]*i; return t; }
constexpr FTab FTB = mkft();

constexpr double csqrt(double x){
  double g = x < 1.0 ? 1.0 : x;
  for(int i=0;i<40;i++) g = 0.5*(g + x/g);
  return g;
}

constexpr double cgcoef(int j1,int m1,int j2,int m2,int j3,int m3){
  if (m1+m2 != m3) return 0.0;
  double pref = csqrt((double)(2*j3+1) * FTB.f[j3+j1-j2] * FTB.f[j3-j1+j2]
                      * FTB.f[j1+j2-j3] / FTB.f[j1+j2+j3+1]);
  pref *= csqrt(FTB.f[j3+m3]*FTB.f[j3-m3]*FTB.f[j1-m1]*FTB.f[j1+m1]
                *FTB.f[j2-m2]*FTB.f[j2+m2]);
  double s = 0.0;
  for(int k=0;k<=j1+j2-j3;k++){
    int e1=j1+j2-j3-k, e2=j1-m1-k, e3=j2+m2-k, e4=j3-j2+m1+k, e5=j3-j1-m2+k;
    if (e1<0||e2<0||e3<0||e4<0||e5<0) continue;
    double prod = FTB.f[k]*FTB.f[e1]*FTB.f[e2]*FTB.f[e3]*FTB.f[e4]*FTB.f[e5];
    s += (k&1) ? (-1.0/prod) : (1.0/prod);
  }
  return pref*s;
}

struct Tab { double v[11][125]; };

constexpr Tab build(){
  Tab T{};
  constexpr int PL1[11]={0,0,0,1,1,1,1,2,2,2,2};
  constexpr int PL2[11]={0,1,2,0,1,1,2,0,1,2,2};
  constexpr int PL3[11]={0,1,2,1,0,2,1,2,1,0,2};
  constexpr int NOUT[3]={3,4,4};
  double qr[3][5][5]{}, qi[3][5][5]{};
  for(int l=0;l<3;l++){
    const double is2 = 0.70710678118654752440;
    for(int m=-l;m<0;m++){ qr[l][l+m][l-m]=is2; qi[l][l+m][l+m]=-is2; }
    qr[l][l][l]=1.0;
    for(int m=1;m<=l;m++){ double sg=(m&1)?-1.0:1.0; qr[l][l+m][l+m]=sg*is2; qi[l][l+m][l-m]=sg*is2; }
    if (l==1){ for(int a=0;a<5;a++)for(int b=0;b<5;b++){ double re=qr[1][a][b], im=qi[1][a][b]; qr[1][a][b]=im; qi[1][a][b]=-re; } }
    if (l==2){ for(int a=0;a<5;a++)for(int b=0;b<5;b++){ qr[2][a][b]=-qr[2][a][b]; qi[2][a][b]=-qi[2][a][b]; } }
  }
  for(int p=0;p<11;p++){
    int l1=PL1[p], l2=PL2[p], l3=PL3[p];
    int d1=2*l1+1, d2=2*l2+1, d3=2*l3+1;
    double cs[125]{};
    for(int i=0;i<d1;i++)for(int k=0;k<d2;k++)for(int m=0;m<d3;m++)
      cs[(i*d2+k)*d3+m] = cgcoef(l1,i-l1,l2,k-l2,l3,m-l3);
    double nrm2 = 0.0;
    for(int j=0;j<d1;j++)for(int lc=0;lc<d2;lc++)for(int n=0;n<d3;n++){
      double ar = 0.0;
      for(int i=0;i<d1;i++){
        double q1r=qr[l1][i][j], q1i=qi[l1][i][j];
        if (q1r==0.0 && q1i==0.0) continue;
        for(int k=0;k<d2;k++){
          double q2r=qr[l2][k][lc], q2i=qi[l2][k][lc];
          if (q2r==0.0 && q2i==0.0) continue;
          double abr=q1r*q2r-q1i*q2i, abi=q1r*q2i+q1i*q2r;
          for(int m=0;m<d3;m++){
            double c=cs[(i*d2+k)*d3+m];
            if (c==0.0) continue;
            double q3r=qr[l3][m][n], q3i=-qi[l3][m][n];   // conj(q3)
            ar += (abr*q3r - abi*q3i)*c;
          }
        }
      }
      T.v[p][(j*d2+lc)*d3+n] = ar;
      nrm2 += ar*ar;
    }
    double sc = csqrt((double)(2*l3+1)/(double)NOUT[l3]) / csqrt(nrm2);
    for(int e=0;e<d1*d2*d3;e++) T.v[p][e] *= sc;
  }
  return T;
}

constexpr Tab CGT = build();

} // namespace cgc

// ======================================================================
// Sparse per-path TP: coefficients are literals, zeros DCE'd.
// ======================================================================
template<int P,int L1,int L2,int L3>
__device__ __forceinline__ void tp_path(float wp, const float (&xi)[9],
                                        const float (&yi)[9], float (&o)[9])
{
  constexpr int D1=2*L1+1, D2=2*L2+1, D3=2*L3+1, O1=L1*L1, O2=L2*L2, O3=L3*L3;
  float z[D3];
#pragma unroll
  for(int k=0;k<D3;k++) z[k]=0.f;
#pragma unroll
  for(int i=0;i<D1;i++){
#pragma unroll
    for(int j=0;j<D2;j++){
      const float tt = xi[O1+i]*yi[O2+j];
#pragma unroll
      for(int k=0;k<D3;k++){
        const double cv = cgc::CGT.v[P][(i*D2+j)*D3+k];
        if (cv > 1e-12 || cv < -1e-12)
          z[k] = fmaf((float)cv, tt, z[k]);
      }
    }
  }
#pragma unroll
  for(int k=0;k<D3;k++) o[O3+k] = fmaf(wp, z[k], o[O3+k]);
}

struct Vec9 { vf4 a, b; float s; };

// ======================================================================
// Setup: transpose W_lin [f=32][c*11+p] -> ws [f=32][c=32][12] so each
// (f,c) row is three ALIGNED dwordx4. ~2us, graph-safe, every launch.
// ======================================================================
__global__ __launch_bounds__(256, 1) void w_transpose(
    const float* __restrict__ Wl, float* __restrict__ ws)
{
  for (int i = threadIdx.x; i < 32*352; i += 256){
    const int f = i / 352, rm = i - f*352;
    const int c = rm / 11, p = rm - c*11;
    ws[f*384 + c*12 + p] = Wl[i];
  }
}

// ======================================================================
// Main kernel: ZERO LDS, ZERO barriers. W read directly from global
// (45 KB, L2/L3-resident across all 4096 blocks); dist read directly
// (L1-hot per block). Every wave fully independent -> counted-vmcnt
// software pipelining + TLP hide latency. Occupancy VGPR-bound only.
// ======================================================================
__global__ __launch_bounds__(256, 3) void e3_tp_kernel(
    const float* __restrict__ x, const float* __restrict__ y,
    const float* __restrict__ dist, const float* __restrict__ Wt,
    const float* __restrict__ bias, float* __restrict__ out)
{
  const int t = threadIdx.x;
  const int c = t & 31, g = t >> 5;
  const long bblk = (long)blockIdx.x * 32;
  const long b0 = bblk + g*4;
  const long ib = b0*32 + c;

  // ---- bias init ----
  float w[4][11];
  {
    const float* bp = bias + c*11;
    vf4 ba, bb2;
    __builtin_memcpy(&ba,  bp,   16);
    __builtin_memcpy(&bb2, bp+4, 16);
    const float bl[11] = {ba.x,ba.y,ba.z,ba.w, bb2.x,bb2.y,bb2.z,bb2.w,
                          bp[8], bp[9], bp[10]};
#pragma unroll
    for (int p = 0; p < 11; p++){
#pragma unroll
      for (int r = 0; r < 4; r++) w[r][p] = bl[p];
    }
  }

  // ---- fused linear, direct global W (uniform f-base + per-lane c off) ----
  const float* db = dist + b0*32;
  const float* wt = Wt + c*12;           // f stride = 384 floats
#pragma unroll 2
  for (int fq = 0; fq < 8; fq++){
    vf4 dd[4];
#pragma unroll
    for (int r = 0; r < 4; r++)
      __builtin_memcpy(&dd[r], db + r*32 + fq*4, 16);
#pragma unroll
    for (int ff = 0; ff < 4; ff++){
      const float* wr = wt + (fq*4 + ff)*384;
      vf4 wa, wb2, wc2;
      __builtin_memcpy(&wa,  wr,   16);   // aligned dwordx4
      __builtin_memcpy(&wb2, wr+4, 16);
      __builtin_memcpy(&wc2, wr+8, 16);
      const float wl[11] = {wa.x,wa.y,wa.z,wa.w, wb2.x,wb2.y,wb2.z,wb2.w,
                            wc2.x,wc2.y,wc2.z};
#pragma unroll
      for (int r = 0; r < 4; r++){
        const float dv = (ff==0) ? dd[r].x : (ff==1) ? dd[r].y
                       : (ff==2) ? dd[r].z : dd[r].w;
#pragma unroll
        for (int p = 0; p < 11; p++) w[r][p] = fmaf(dv, wl[p], w[r][p]);
      }
    }
  }

  // ---- per-item tensor product, 2-deep load pipeline ----
  auto ldv9 = [](const float* p) {
    Vec9 v;
    __builtin_memcpy(&v.a, p,   16);
    __builtin_memcpy(&v.b, p+4, 16);
    v.s = p[8];
    return v;
  };

  float* op = out + ib*9;

  auto tpstore = [&](const Vec9& xv, const Vec9& yv,
                     const float (&wr)[11], float* o0) {
    const float xi[9] = {xv.a.x,xv.a.y,xv.a.z,xv.a.w,
                         xv.b.x,xv.b.y,xv.b.z,xv.b.w, xv.s};
    const float yi[9] = {yv.a.x,yv.a.y,yv.a.z,yv.a.w,
                         yv.b.x,yv.b.y,yv.b.z,yv.b.w, yv.s};
    float o[9];
#pragma unroll
    for (int k = 0; k < 9; k++) o[k] = 0.f;
    tp_path<0, 0,0,0>(wr[0],  xi, yi, o);
    tp_path<1, 0,1,1>(wr[1],  xi, yi, o);
    tp_path<2, 0,2,2>(wr[2],  xi, yi, o);
    tp_path<3, 1,0,1>(wr[3],  xi, yi, o);
    tp_path<4, 1,1,0>(wr[4],  xi, yi, o);
    tp_path<5, 1,1,2>(wr[5],  xi, yi, o);
    tp_path<6, 1,2,1>(wr[6],  xi, yi, o);
    tp_path<7, 2,0,2>(wr[7],  xi, yi, o);
    tp_path<8, 2,1,1>(wr[8],  xi, yi, o);
    tp_path<9, 2,2,0>(wr[9],  xi, yi, o);
    tp_path<10,2,2,2>(wr[10], xi, yi, o);
    vf4 s0 = { o[0], o[1], o[2], o[3] };
    vf4 s1 = { o[4], o[5], o[6], o[7] };
    __builtin_memcpy(o0,     &s0, 16);
    __builtin_memcpy(o0 + 4, &s1, 16);
    o0[8] = o[8];
  };

  Vec9 xa = ldv9(x + ib*9),       ya = ldv9(y + ib*9);
  Vec9 xb = ldv9(x + ib*9 + 288), yb = ldv9(y + ib*9 + 288);
  tpstore(xa, ya, w[0], op);
  xa = ldv9(x + ib*9 + 576); ya = ldv9(y + ib*9 + 576);
  tpstore(xb, yb, w[1], op + 288);
  xb = ldv9(x + ib*9 + 864); yb = ldv9(y + ib*9 + 864);
  tpstore(xa, ya, w[2], op + 576);
  tpstore(xb, yb, w[3], op + 864);
}

extern "C" void kernel_launch(void* const* d_in, const int* in_sizes, int n_in,
                              void* d_out, int out_size, void* d_ws, size_t ws_size,
                              hipStream_t stream)
{
  const float* x    = (const float*)d_in[0];
  const float* y    = (const float*)d_in[1];
  const float* dist = (const float*)d_in[2];
  const float* Wl   = (const float*)d_in[3];
  const float* bl   = (const float*)d_in[4];
  float* out = (float*)d_out;
  float* ws  = (float*)d_ws;               // 48 KB: W as [f][c][12]

  hipLaunchKernelGGL(w_transpose, dim3(1), dim3(256), 0, stream, Wl, ws);

  const int B = in_sizes[2] / 32;          // 131072 rows
  const int nblocks = B / 32;              // 32 b's x 32 c's per block
  hipLaunchKernelGGL(e3_tp_kernel, dim3(nblocks), dim3(256), 0, stream,
                     x, y, dist, ws, bl, out);
}

// Round 7
// 123.054 us; speedup vs baseline: 1.7869x; 1.2911x over previous
//
#include <hip/hip_runtime.h>

typedef float vf4 __attribute__((ext_vector_type(4)));

// ======================================================================
// Compile-time CG table (validated rounds 1-6): real-SH CG build in fp64
// via constexpr. Coefficients fold to literals; zeros DCE away.
// ======================================================================
namespace cgc {

struct FTab { double f[13]; };
constexpr FTab mkft(){ FTab t{}; t.f[0]=1.0; for(int i=1;i<13;i++) t.f[i]=t.f[i-1]*i; return t; }
constexpr FTab FTB = mkft();

constexpr double csqrt(double x){
  double g = x < 1.0 ? 1.0 : x;
  for(int i=0;i<40;i++) g = 0.5*(g + x/g);
  return g;
}

constexpr double cgcoef(int j1,int m1,int j2,int m2,int j3,int m3){
  if (m1+m2 != m3) return 0.0;
  double pref = csqrt((double)(2*j3+1) * FTB.f[j3+j1-j2] * FTB.f[j3-j1+j2]
                      * FTB.f[j1+j2-j3] / FTB.f[j1+j2+j3+1]);
  pref *= csqrt(FTB.f[j3+m3]*FTB.f[j3-m3]*FTB.f[j1-m1]*FTB.f[j1+m1]
                *FTB.f[j2-m2]*FTB.f[j2+m2]);
  double s = 0.0;
  for(int k=0;k<=j1+j2-j3;k++){
    int e1=j1+j2-j3-k, e2=j1-m1-k, e3=j2+m2-k, e4=j3-j2+m1+k, e5=j3-j1-m2+k;
    if (e1<0||e2<0||e3<0||e4<0||e5<0) continue;
    double prod = FTB.f[k]*FTB.f[e1]*FTB.f[e2]*FTB.f[e3]*FTB.f[e4]*FTB.f[e5];
    s += (k&1) ? (-1.0/prod) : (1.0/prod);
  }
  return pref*s;
}

struct Tab { double v[11][125]; };

constexpr Tab build(){
  Tab T{};
  constexpr int PL1[11]={0,0,0,1,1,1,1,2,2,2,2};
  constexpr int PL2[11]={0,1,2,0,1,1,2,0,1,2,2};
  constexpr int PL3[11]={0,1,2,1,0,2,1,2,1,0,2};
  constexpr int NOUT[3]={3,4,4};
  double qr[3][5][5]{}, qi[3][5][5]{};
  for(int l=0;l<3;l++){
    const double is2 = 0.70710678118654752440;
    for(int m=-l;m<0;m++){ qr[l][l+m][l-m]=is2; qi[l][l+m][l+m]=-is2; }
    qr[l][l][l]=1.0;
    for(int m=1;m<=l;m++){ double sg=(m&1)?-1.0:1.0; qr[l][l+m][l+m]=sg*is2; qi[l][l+m][l-m]=sg*is2; }
    if (l==1){ for(int a=0;a<5;a++)for(int b=0;b<5;b++){ double re=qr[1][a][b], im=qi[1][a][b]; qr[1][a][b]=im; qi[1][a][b]=-re; } }
    if (l==2){ for(int a=0;a<5;a++)for(int b=0;b<5;b++){ qr[2][a][b]=-qr[2][a][b]; qi[2][a][b]=-qi[2][a][b]; } }
  }
  for(int p=0;p<11;p++){
    int l1=PL1[p], l2=PL2[p], l3=PL3[p];
    int d1=2*l1+1, d2=2*l2+1, d3=2*l3+1;
    double cs[125]{};
    for(int i=0;i<d1;i++)for(int k=0;k<d2;k++)for(int m=0;m<d3;m++)
      cs[(i*d2+k)*d3+m] = cgcoef(l1,i-l1,l2,k-l2,l3,m-l3);
    double nrm2 = 0.0;
    for(int j=0;j<d1;j++)for(int lc=0;lc<d2;lc++)for(int n=0;n<d3;n++){
      double ar = 0.0;
      for(int i=0;i<d1;i++){
        double q1r=qr[l1][i][j], q1i=qi[l1][i][j];
        if (q1r==0.0 && q1i==0.0) continue;
        for(int k=0;k<d2;k++){
          double q2r=qr[l2][k][lc], q2i=qi[l2][k][lc];
          if (q2r==0.0 && q2i==0.0) continue;
          double abr=q1r*q2r-q1i*q2i, abi=q1r*q2i+q1i*q2r;
          for(int m=0;m<d3;m++){
            double c=cs[(i*d2+k)*d3+m];
            if (c==0.0) continue;
            double q3r=qr[l3][m][n], q3i=-qi[l3][m][n];   // conj(q3)
            ar += (abr*q3r - abi*q3i)*c;
          }
        }
      }
      T.v[p][(j*d2+lc)*d3+n] = ar;
      nrm2 += ar*ar;
    }
    double sc = csqrt((double)(2*l3+1)/(double)NOUT[l3]) / csqrt(nrm2);
    for(int e=0;e<d1*d2*d3;e++) T.v[p][e] *= sc;
  }
  return T;
}

constexpr Tab CGT = build();

} // namespace cgc

// ======================================================================
// Sparse per-path TP: coefficients are literals, zeros DCE'd.
// ======================================================================
template<int P,int L1,int L2,int L3>
__device__ __forceinline__ void tp_path(float wp, const float (&xi)[9],
                                        const float (&yi)[9], float (&o)[9])
{
  constexpr int D1=2*L1+1, D2=2*L2+1, D3=2*L3+1, O1=L1*L1, O2=L2*L2, O3=L3*L3;
  float z[D3];
#pragma unroll
  for(int k=0;k<D3;k++) z[k]=0.f;
#pragma unroll
  for(int i=0;i<D1;i++){
#pragma unroll
    for(int j=0;j<D2;j++){
      const float tt = xi[O1+i]*yi[O2+j];
#pragma unroll
      for(int k=0;k<D3;k++){
        const double cv = cgc::CGT.v[P][(i*D2+j)*D3+k];
        if (cv > 1e-12 || cv < -1e-12)
          z[k] = fmaf((float)cv, tt, z[k]);
      }
    }
  }
#pragma unroll
  for(int k=0;k<D3;k++) o[O3+k] = fmaf(wp, z[k], o[O3+k]);
}

struct Vec9 { vf4 a, b; float s; };

// ======================================================================
// Persistent-ish kernel: stage FULL W (48 KB) to LDS once (1 barrier),
// then 4 barrier-free b-tiles of 32 per block. W L2 traffic 1.6GB->50MB;
// steady state has no syncs so loads pipeline across tiles.
// Block = 256 thr: c = t&31, g = t>>5 (8 groups x R=4). 1024 blocks.
// ======================================================================
#define NTILE 4

__global__ __launch_bounds__(256, 3) void e3_tp_kernel(
    const float* __restrict__ x, const float* __restrict__ y,
    const float* __restrict__ dist, const float* __restrict__ Wl,
    const float* __restrict__ bias, float* __restrict__ out)
{
  __shared__ float Ws[32*32*12];         // [f=32][c=32][12], 48 KB
  const vf4* Ws4 = (const vf4*)Ws;
  const int t = threadIdx.x;
  const int c = t & 31, g = t >> 5;
  const long bbase = (long)blockIdx.x * (32*NTILE);

  // ---- stage FULL W once: 11264 floats, 44/thread, coalesced ----
  for (int i = t; i < 32*352; i += 256){
    const int f = i / 352, rm = i - f*352;
    const int cc = rm / 11, p = rm - cc*11;
    Ws[f*384 + cc*12 + p] = Wl[i];
  }

  // ---- bias (needed every tile) ----
  float bl[11];
  {
    const float* bp = bias + c*11;
    vf4 ba, bb2;
    __builtin_memcpy(&ba,  bp,   16);
    __builtin_memcpy(&bb2, bp+4, 16);
    bl[0]=ba.x; bl[1]=ba.y; bl[2]=ba.z; bl[3]=ba.w;
    bl[4]=bb2.x; bl[5]=bb2.y; bl[6]=bb2.z; bl[7]=bb2.w;
    bl[8]=bp[8]; bl[9]=bp[9]; bl[10]=bp[10];
  }

  __syncthreads();                       // ONLY barrier in the kernel

  auto ldv9 = [](const float* p) {
    Vec9 v;
    __builtin_memcpy(&v.a, p,   16);
    __builtin_memcpy(&v.b, p+4, 16);
    v.s = p[8];
    return v;
  };

  auto tpstore = [&](const Vec9& xv, const Vec9& yv,
                     const float (&wr)[11], float* o0) {
    const float xi[9] = {xv.a.x,xv.a.y,xv.a.z,xv.a.w,
                         xv.b.x,xv.b.y,xv.b.z,xv.b.w, xv.s};
    const float yi[9] = {yv.a.x,yv.a.y,yv.a.z,yv.a.w,
                         yv.b.x,yv.b.y,yv.b.z,yv.b.w, yv.s};
    float o[9];
#pragma unroll
    for (int k = 0; k < 9; k++) o[k] = 0.f;
    tp_path<0, 0,0,0>(wr[0],  xi, yi, o);
    tp_path<1, 0,1,1>(wr[1],  xi, yi, o);
    tp_path<2, 0,2,2>(wr[2],  xi, yi, o);
    tp_path<3, 1,0,1>(wr[3],  xi, yi, o);
    tp_path<4, 1,1,0>(wr[4],  xi, yi, o);
    tp_path<5, 1,1,2>(wr[5],  xi, yi, o);
    tp_path<6, 1,2,1>(wr[6],  xi, yi, o);
    tp_path<7, 2,0,2>(wr[7],  xi, yi, o);
    tp_path<8, 2,1,1>(wr[8],  xi, yi, o);
    tp_path<9, 2,2,0>(wr[9],  xi, yi, o);
    tp_path<10,2,2,2>(wr[10], xi, yi, o);
    vf4 s0 = { o[0], o[1], o[2], o[3] };
    vf4 s1 = { o[4], o[5], o[6], o[7] };
    __builtin_memcpy(o0,     &s0, 16);
    __builtin_memcpy(o0 + 4, &s1, 16);
    o0[8] = o[8];
  };

  const vf4* wsrow = Ws4 + c*3;          // c*12 floats = 3 vf4

#pragma unroll 1
  for (int tile = 0; tile < NTILE; tile++){
    const long b0 = bbase + tile*32 + g*4;
    const long ib = b0*32 + c;

    // ---- fused linear from LDS W + direct dist ----
    float w[4][11];
#pragma unroll
    for (int p = 0; p < 11; p++){
#pragma unroll
      for (int r = 0; r < 4; r++) w[r][p] = bl[p];
    }

    const float* db = dist + b0*32;
#pragma unroll 2
    for (int fq = 0; fq < 8; fq++){
      vf4 dd[4];
#pragma unroll
      for (int r = 0; r < 4; r++)
        __builtin_memcpy(&dd[r], db + r*32 + fq*4, 16);
#pragma unroll
      for (int ff = 0; ff < 4; ff++){
        const vf4* wr = wsrow + (fq*4 + ff)*96;  // f stride = 384 fl = 96 vf4
        const vf4 wa = wr[0], wb2 = wr[1], wc2 = wr[2];
        const float wl[11] = {wa.x,wa.y,wa.z,wa.w, wb2.x,wb2.y,wb2.z,wb2.w,
                              wc2.x,wc2.y,wc2.z};
#pragma unroll
        for (int r = 0; r < 4; r++){
          const float dv = (ff==0) ? dd[r].x : (ff==1) ? dd[r].y
                         : (ff==2) ? dd[r].z : dd[r].w;
#pragma unroll
          for (int p = 0; p < 11; p++) w[r][p] = fmaf(dv, wl[p], w[r][p]);
        }
      }
    }

    // ---- TP with 2-deep x/y pipeline ----
    const float* xp = x + ib*9;
    const float* yp = y + ib*9;
    float* op = out + ib*9;

    Vec9 xa = ldv9(xp),       ya = ldv9(yp);
    Vec9 xb = ldv9(xp + 288), yb = ldv9(yp + 288);
    tpstore(xa, ya, w[0], op);
    xa = ldv9(xp + 576); ya = ldv9(yp + 576);
    tpstore(xb, yb, w[1], op + 288);
    xb = ldv9(xp + 864); yb = ldv9(yp + 864);
    tpstore(xa, ya, w[2], op + 576);
    tpstore(xb, yb, w[3], op + 864);
  }
}

extern "C" void kernel_launch(void* const* d_in, const int* in_sizes, int n_in,
                              void* d_out, int out_size, void* d_ws, size_t ws_size,
                              hipStream_t stream)
{
  const float* x    = (const float*)d_in[0];
  const float* y    = (const float*)d_in[1];
  const float* dist = (const float*)d_in[2];
  const float* Wl   = (const float*)d_in[3];
  const float* bl   = (const float*)d_in[4];
  float* out = (float*)d_out;

  const int B = in_sizes[2] / 32;            // 131072 rows
  const int nblocks = B / (32*NTILE);        // 1024 blocks
  hipLaunchKernelGGL(e3_tp_kernel, dim3(nblocks), dim3(256), 0, stream,
                     x, y, dist, Wl, bl, out);
}